// Round 9
// baseline (407.547 us; speedup 1.0000x reference)
//
#include <hip/hip_runtime.h>
#include <math.h>

#define EPS_F 1e-7f

constexpr int Bc = 32, Tc = 8192, Kc = 16;
constexpr int ROWS  = Bc * Tc;        // 262144
constexpr int BLOCK = 256;
constexpr int ROWS_PER_BLK = BLOCK / 4;     // 64 rows per block (4 thr/row)
constexpr int NBLK  = ROWS / ROWS_PER_BLK;  // 4096 blocks

typedef unsigned long long u64;

__device__ __forceinline__ u64 shflx64(u64 v, int m) {
  unsigned lo = __shfl_xor((unsigned)v, m, 64);
  unsigned hi = __shfl_xor((unsigned)(v >> 32), m, 64);
  return ((u64)hi << 32) | lo;
}

// R3 champion structure (66us, VGPR 32, occ 63% -- every structural
// deviation in R4-R8 regressed) + fused finalize via last-block-done.
// ws layout: [0]=counter(u32, memset 0 by host), 16B.. = [NBLK][6] partials.
__global__ __launch_bounds__(BLOCK) void loss_main(
    const float* __restrict__ trig,
    const float* __restrict__ valp,
    const float* __restrict__ clog,
    const float* __restrict__ wscore,
    const int*   __restrict__ live,
    const int*   __restrict__ cid,
    const float* __restrict__ ofire,
    const int*   __restrict__ ocan,
    const float* __restrict__ ovalid,
    const float* __restrict__ oshw,
    const int*   __restrict__ ocid,
    unsigned*    __restrict__ counter,   // zeroed before launch
    float* __restrict__ part,            // [NBLK][6]
    float* __restrict__ out)             // 5 outputs
{
  const int t    = blockIdx.x * BLOCK + threadIdx.x;  // global vec4 index
  const int lane = threadIdx.x & 63;

  // ---- all loads up front (R3 exact)
  const int4   oc = ((const int4*)  ocid)[t];
  const int4   cc = ((const int4*)  ocan)[t];
  const float4 ff = ((const float4*)ofire)[t];
  const float4 vv = ((const float4*)ovalid)[t];
  const int4   cd = ((const int4*)  cid)[t];
  const int4   lm = ((const int4*)  live)[t];
  const float4 ph = ((const float4*)trig)[t];
  const float4 pq = ((const float4*)valp)[t];
  const float4 lA = ((const float4*)clog)[t * 3 + 0];
  const float4 lB = ((const float4*)clog)[t * 3 + 1];
  const float4 lC = ((const float4*)clog)[t * 3 + 2];
  float ws_x = 0.f, ws_y = 0.f;
  if (threadIdx.x < ROWS_PER_BLK) {
    const int r2 = blockIdx.x * ROWS_PER_BLK + threadIdx.x;
    ws_x = wscore[r2];
    ws_y = oshw[r2];
  }

  // ---- per-lane partial oracle table (my 4 slots, slot order)
  u64 tblLo = 0ull, tblHi = 0ull, fndLo = 0ull, fndHi = 0ull;
  {
    const int   ocs[4] = {oc.x, oc.y, oc.z, oc.w};
    const int   ccs[4] = {cc.x, cc.y, cc.z, cc.w};
    const float ffs[4] = {ff.x, ff.y, ff.z, ff.w};
    const float vvs[4] = {vv.x, vv.y, vv.z, vv.w};
    #pragma unroll
    for (int j = 0; j < 4; ++j) {
      const unsigned c  = (unsigned)ocs[j] & 31u;
      const unsigned sh = (c & 15u) * 4u;
      const bool isLo   = c < 16u;
      const bool seen   = (((isLo ? fndLo : fndHi) >> sh) & 1ull) != 0ull;
      const unsigned nib = (unsigned)ffs[j] | ((unsigned)vvs[j] << 1) |
                           ((unsigned)ccs[j] << 2);
      const u64 add  = seen ? 0ull : ((u64)nib << sh);
      const u64 fadd = 0xFull << sh;
      tblLo |= isLo ? add : 0ull;
      tblHi |= isLo ? 0ull : add;
      fndLo |= isLo ? fadd : 0ull;
      fndHi |= isLo ? 0ull : fadd;
    }
  }

  // ---- merge across 4-lane row group (lower lane = earlier slot wins)
  #pragma unroll
  for (int m = 1; m <= 2; m <<= 1) {
    const u64 pTL = shflx64(tblLo, m);
    const u64 pTH = shflx64(tblHi, m);
    const u64 pFL = shflx64(fndLo, m);
    const u64 pFH = shflx64(fndHi, m);
    const bool iLow = (lane & m) == 0;
    const u64 loTL = iLow ? tblLo : pTL, hiTL = iLow ? pTL : tblLo;
    const u64 loTH = iLow ? tblHi : pTH, hiTH = iLow ? pTH : tblHi;
    const u64 loFL = iLow ? fndLo : pFL, hiFL = iLow ? pFL : fndLo;
    const u64 loFH = iLow ? fndHi : pFH, hiFH = iLow ? pFH : fndHi;
    tblLo = loTL | (hiTL & ~loFL);
    tblHi = loTH | (hiTH & ~loFH);
    fndLo = loFL | hiFL;
    fndHi = loFH | hiFH;
  }

  // ---- losses for my 4 slots (R3 exact)
  float s0 = 0.f, s1 = 0.f, s2 = 0.f, s3 = 0.f, s4 = 0.f;
  {
    const int   cds[4] = {cd.x, cd.y, cd.z, cd.w};
    const int   lms[4] = {lm.x, lm.y, lm.z, lm.w};
    const float phs[4] = {ph.x, ph.y, ph.z, ph.w};
    const float pqs[4] = {pq.x, pq.y, pq.z, pq.w};
    const float L0[4] = {lA.x, lA.w, lB.z, lC.y};
    const float L1[4] = {lA.y, lB.x, lB.w, lC.z};
    const float L2[4] = {lA.z, lB.y, lC.x, lC.w};
    #pragma unroll
    for (int j = 0; j < 4; ++j) {
      const unsigned c  = (unsigned)cds[j] & 31u;
      const unsigned sh = (c & 15u) * 4u;
      const bool isLo   = c < 16u;
      const bool fnd = (c != 0u) &&
                       ((((isLo ? fndLo : fndHi) >> sh) & 1ull) != 0ull);
      unsigned nib = (unsigned)(((isLo ? tblLo : tblHi) >> sh)) & 15u;
      nib = fnd ? nib : 0u;
      const float fire_t = (float)(nib & 1u);
      const float val_t  = (float)((nib >> 1) & 1u);
      const int   can_t  = (int)(nib >> 2);

      const float m = lms[j] ? 1.f : 0.f;

      const float p  = fminf(fmaxf(phs[j], EPS_F), 1.f - EPS_F);
      const float bf = -__logf((fire_t != 0.f) ? p : 1.f - p);
      const float q  = fminf(fmaxf(pqs[j], EPS_F), 1.f - EPS_F);
      const float bv = -__logf((val_t != 0.f) ? q : 1.f - q);

      const float has = (can_t > 0 && lms[j]) ? 1.f : 0.f;
      const int tgt = (can_t - 1) < 0 ? 0 : (can_t - 1);
      const float l0 = L0[j], l1 = L1[j], l2 = L2[j];
      const float mx  = fmaxf(l0, fmaxf(l1, l2));
      const float lse = mx + __logf(__expf(l0 - mx) + __expf(l1 - mx) +
                                    __expf(l2 - mx));
      const float lt  = (tgt == 0) ? l0 : ((tgt == 1) ? l1 : l2);

      s0 += bf * m;
      s1 += m;
      s2 += (lse - lt) * has;
      s3 += has;
      s4 += bv * m;
    }
  }

  // ---- write term (first 64 threads cover the block's 64 rows)
  float s5 = 0.f;
  if (threadIdx.x < ROWS_PER_BLK) {
    s5 = fmaxf(ws_x, 0.f) - ws_x * ws_y + __logf(1.f + __expf(-fabsf(ws_x)));
  }

  // ---- wave reduce, then block reduce via LDS
  float v[6] = {s0, s1, s2, s3, s4, s5};
  #pragma unroll
  for (int off = 32; off > 0; off >>= 1) {
    #pragma unroll
    for (int i = 0; i < 6; ++i) v[i] += __shfl_down(v[i], off, 64);
  }
  __shared__ float red[4][6];
  const int w = threadIdx.x >> 6;
  if (lane == 0) {
    #pragma unroll
    for (int i = 0; i < 6; ++i) red[w][i] = v[i];
  }
  __syncthreads();

  // ---- publish partial + last-block-done fused finalize
  __shared__ unsigned amLast;
  if (threadIdx.x == 0) {
    #pragma unroll
    for (int i = 0; i < 6; ++i)
      part[blockIdx.x * 6 + i] = red[0][i] + red[1][i] + red[2][i] + red[3][i];
    __threadfence();                             // release partials
    amLast = (atomicAdd(counter, 1u) == (unsigned)(NBLK - 1));
  }
  __syncthreads();
  if (amLast) {
    __threadfence();                             // acquire others' partials
    double a[6] = {0, 0, 0, 0, 0, 0};
    for (int r = threadIdx.x; r < NBLK; r += BLOCK) {
      #pragma unroll
      for (int i = 0; i < 6; ++i) a[i] += (double)part[r * 6 + i];
    }
    #pragma unroll
    for (int off = 32; off > 0; off >>= 1) {
      #pragma unroll
      for (int i = 0; i < 6; ++i) a[i] += __shfl_down(a[i], off, 64);
    }
    __shared__ double dred[4][6];
    if (lane == 0) {
      #pragma unroll
      for (int i = 0; i < 6; ++i) dred[w][i] = a[i];
    }
    __syncthreads();
    if (threadIdx.x == 0) {
      double f[6];
      #pragma unroll
      for (int i = 0; i < 6; ++i)
        f[i] = dred[0][i] + dred[1][i] + dred[2][i] + dred[3][i];
      const double live_n = f[1] < 1.0 ? 1.0 : f[1];
      const double fire   = f[0] / live_n;                                  // LAM_FIRE   = 1.0
      const double cancel = (f[3] > 0.0) ? f[2] / (f[3] < 1.0 ? 1.0 : f[3]) // LAM_CANCEL = 1.0
                                         : 0.0;
      const double valid  = 0.5 * f[4] / live_n;                            // LAM_VALID  = 0.5
      const double wr     = 0.5 * f[5] / (double)ROWS;                      // LAM_WRITE  = 0.5
      out[0] = (float)fire;
      out[1] = (float)cancel;
      out[2] = (float)valid;
      out[3] = (float)wr;
      out[4] = (float)(fire + cancel + valid + wr);
    }
  }
}

extern "C" void kernel_launch(void* const* d_in, const int* in_sizes, int n_in,
                              void* d_out, int out_size, void* d_ws, size_t ws_size,
                              hipStream_t stream) {
  const float* trig   = (const float*)d_in[0];
  const float* valp   = (const float*)d_in[1];
  const float* clog   = (const float*)d_in[2];
  const float* wscore = (const float*)d_in[3];
  const int*   live   = (const int*)  d_in[4];
  const int*   cid    = (const int*)  d_in[5];
  const float* ofire  = (const float*)d_in[6];
  const int*   ocan   = (const int*)  d_in[7];
  const float* ovalid = (const float*)d_in[8];
  const float* oshw   = (const float*)d_in[9];
  const int*   ocid   = (const int*)  d_in[10];
  float* out = (float*)d_out;

  unsigned* counter = (unsigned*)d_ws;                 // [0..4)
  float*    part    = (float*)((char*)d_ws + 16);      // [NBLK][6] = 96 KB

  // counter must start at 0 every call (ws is poisoned 0xAA); async memset
  // is graph-capture legal.
  hipMemsetAsync(counter, 0, sizeof(unsigned), stream);

  loss_main<<<NBLK, BLOCK, 0, stream>>>(trig, valp, clog, wscore, live, cid,
                                        ofire, ocan, ovalid, oshw, ocid,
                                        counter, part, out);
}

// Round 10
// 210.314 us; speedup vs baseline: 1.9378x; 1.9378x over previous
//
#include <hip/hip_runtime.h>
#include <math.h>

#define EPS_F 1e-7f

constexpr int Bc = 32, Tc = 8192, Kc = 16;
constexpr int ROWS  = Bc * Tc;           // 262144
constexpr int BLOCK = 256;
constexpr int ROWS_PER_BLK = BLOCK / 4;  // 64 rows per block (4 threads/row)
constexpr int NBLK  = ROWS / ROWS_PER_BLK;  // 4096 blocks

typedef unsigned long long u64;

__device__ __forceinline__ u64 shflx64(u64 v, int m) {
  unsigned lo = __shfl_xor((unsigned)v, m, 64);
  unsigned hi = __shfl_xor((unsigned)(v >> 32), m, 64);
  return ((u64)hi << 32) | lo;
}

// R3 champion, restored verbatim. Session evidence (R3-R9):
//  - 8 structural variants (occ 17-64%, VGPR 28-100, reg loads / LDS-DMA /
//    vmcnt(12) pipeline / fused finalize) all pin effective read BW at
//    ~2.7-2.8 TB/s; this flat 4-threads-per-row shape is the fastest.
//  - R9: last-block-done finalize with __threadfence() = device-scope L2
//    flush per block -> 4x regression. Keep the tiny second dispatch.
__global__ __launch_bounds__(BLOCK) void loss_main(
    const float* __restrict__ trig,    // trigger_hazard (B,T,K)
    const float* __restrict__ valp,    // validity       (B,T,K)
    const float* __restrict__ clog,    // cancel_logits  (B,T,K,3)
    const float* __restrict__ wscore,  // write_score    (B,T,1)
    const int*   __restrict__ live,    // live_mask      (B,T,K) 0/1
    const int*   __restrict__ cid,     // contract_id    (B,T,K)
    const float* __restrict__ ofire,   // oracle_fire    (B,T,K)
    const int*   __restrict__ ocan,    // oracle_cancel  (B,T,K)
    const float* __restrict__ ovalid,  // oracle_valid   (B,T,K)
    const float* __restrict__ oshw,    // oracle_should_write (B,T,1)
    const int*   __restrict__ ocid,    // oracle_contract_id (B,T,K)
    float* __restrict__ part)          // [NBLK][6] partials
{
  const int t    = blockIdx.x * BLOCK + threadIdx.x;  // global vec4 index
  const int lane = threadIdx.x & 63;

  // ---- issue ALL loads up front
  const int4   oc = ((const int4*)  ocid)[t];
  const int4   cc = ((const int4*)  ocan)[t];
  const float4 ff = ((const float4*)ofire)[t];
  const float4 vv = ((const float4*)ovalid)[t];
  const int4   cd = ((const int4*)  cid)[t];
  const int4   lm = ((const int4*)  live)[t];
  const float4 ph = ((const float4*)trig)[t];
  const float4 pq = ((const float4*)valp)[t];
  const float4 lA = ((const float4*)clog)[t * 3 + 0];
  const float4 lB = ((const float4*)clog)[t * 3 + 1];
  const float4 lC = ((const float4*)clog)[t * 3 + 2];
  float ws_x = 0.f, ws_y = 0.f;
  if (threadIdx.x < ROWS_PER_BLK) {
    const int r2 = blockIdx.x * ROWS_PER_BLK + threadIdx.x;
    ws_x = wscore[r2];
    ws_y = oshw[r2];
  }

  // ---- build my partial oracle table (my 4 slots, in slot order)
  u64 tblLo = 0ull, tblHi = 0ull, fndLo = 0ull, fndHi = 0ull;
  {
    const int   ocs[4] = {oc.x, oc.y, oc.z, oc.w};
    const int   ccs[4] = {cc.x, cc.y, cc.z, cc.w};
    const float ffs[4] = {ff.x, ff.y, ff.z, ff.w};
    const float vvs[4] = {vv.x, vv.y, vv.z, vv.w};
    #pragma unroll
    for (int j = 0; j < 4; ++j) {
      const unsigned c  = (unsigned)ocs[j] & 31u;
      const unsigned sh = (c & 15u) * 4u;
      const bool isLo   = c < 16u;
      const bool seen   = (((isLo ? fndLo : fndHi) >> sh) & 1ull) != 0ull;
      const unsigned nib = (unsigned)ffs[j] | ((unsigned)vvs[j] << 1) |
                           ((unsigned)ccs[j] << 2);
      const u64 add  = seen ? 0ull : ((u64)nib << sh);
      const u64 fadd = 0xFull << sh;
      tblLo |= isLo ? add : 0ull;
      tblHi |= isLo ? 0ull : add;
      fndLo |= isLo ? fadd : 0ull;
      fndHi |= isLo ? 0ull : fadd;
    }
  }

  // ---- merge across the 4-lane row group (lower lane = earlier slots wins)
  #pragma unroll
  for (int m = 1; m <= 2; m <<= 1) {
    const u64 pTL = shflx64(tblLo, m);
    const u64 pTH = shflx64(tblHi, m);
    const u64 pFL = shflx64(fndLo, m);
    const u64 pFH = shflx64(fndHi, m);
    const bool iLow = (lane & m) == 0;
    const u64 loTL = iLow ? tblLo : pTL, hiTL = iLow ? pTL : tblLo;
    const u64 loTH = iLow ? tblHi : pTH, hiTH = iLow ? pTH : tblHi;
    const u64 loFL = iLow ? fndLo : pFL, hiFL = iLow ? pFL : fndLo;
    const u64 loFH = iLow ? fndHi : pFH, hiFH = iLow ? pFH : fndHi;
    tblLo = loTL | (hiTL & ~loFL);
    tblHi = loTH | (hiTH & ~loFH);
    fndLo = loFL | hiFL;
    fndHi = loFH | hiFH;
  }

  // ---- per-slot losses for my 4 slots
  float s0 = 0.f, s1 = 0.f, s2 = 0.f, s3 = 0.f, s4 = 0.f;
  {
    const int   cds[4] = {cd.x, cd.y, cd.z, cd.w};
    const int   lms[4] = {lm.x, lm.y, lm.z, lm.w};
    const float phs[4] = {ph.x, ph.y, ph.z, ph.w};
    const float pqs[4] = {pq.x, pq.y, pq.z, pq.w};
    const float L0[4] = {lA.x, lA.w, lB.z, lC.y};
    const float L1[4] = {lA.y, lB.x, lB.w, lC.z};
    const float L2[4] = {lA.z, lB.y, lC.x, lC.w};
    #pragma unroll
    for (int j = 0; j < 4; ++j) {
      const unsigned c  = (unsigned)cds[j] & 31u;
      const unsigned sh = (c & 15u) * 4u;
      const bool isLo   = c < 16u;
      const bool fnd = (c != 0u) &&
                       ((((isLo ? fndLo : fndHi) >> sh) & 1ull) != 0ull);
      unsigned nib = (unsigned)(((isLo ? tblLo : tblHi) >> sh)) & 15u;
      nib = fnd ? nib : 0u;
      const float fire_t = (float)(nib & 1u);
      const float val_t  = (float)((nib >> 1) & 1u);
      const int   can_t  = (int)(nib >> 2);

      const float m = lms[j] ? 1.f : 0.f;

      const float p  = fminf(fmaxf(phs[j], EPS_F), 1.f - EPS_F);
      const float bf = -__logf((fire_t != 0.f) ? p : 1.f - p);
      const float q  = fminf(fmaxf(pqs[j], EPS_F), 1.f - EPS_F);
      const float bv = -__logf((val_t != 0.f) ? q : 1.f - q);

      const float has = (can_t > 0 && lms[j]) ? 1.f : 0.f;
      const int tgt = (can_t - 1) < 0 ? 0 : (can_t - 1);
      const float l0 = L0[j], l1 = L1[j], l2 = L2[j];
      const float mx  = fmaxf(l0, fmaxf(l1, l2));
      const float lse = mx + __logf(__expf(l0 - mx) + __expf(l1 - mx) +
                                    __expf(l2 - mx));
      const float lt  = (tgt == 0) ? l0 : ((tgt == 1) ? l1 : l2);

      s0 += bf * m;
      s1 += m;
      s2 += (lse - lt) * has;
      s3 += has;
      s4 += bv * m;
    }
  }

  // ---- write term (first 64 threads cover the block's 64 rows)
  float s5 = 0.f;
  if (threadIdx.x < ROWS_PER_BLK) {
    s5 = fmaxf(ws_x, 0.f) - ws_x * ws_y + __logf(1.f + __expf(-fabsf(ws_x)));
  }

  // ---- wave reduce (64 lanes), then block reduce via LDS
  float v[6] = {s0, s1, s2, s3, s4, s5};
  #pragma unroll
  for (int off = 32; off > 0; off >>= 1) {
    #pragma unroll
    for (int i = 0; i < 6; ++i) v[i] += __shfl_down(v[i], off, 64);
  }
  __shared__ float red[4][6];
  const int w = threadIdx.x >> 6;
  if (lane == 0) {
    #pragma unroll
    for (int i = 0; i < 6; ++i) red[w][i] = v[i];
  }
  __syncthreads();
  if (threadIdx.x == 0) {
    #pragma unroll
    for (int i = 0; i < 6; ++i)
      part[blockIdx.x * 6 + i] = red[0][i] + red[1][i] + red[2][i] + red[3][i];
  }
}

// Reduce NBLK partials in double, compute the 5 outputs.
__global__ __launch_bounds__(BLOCK) void loss_finalize(
    const float* __restrict__ part, float* __restrict__ out)
{
  double v[6] = {0, 0, 0, 0, 0, 0};
  for (int r = threadIdx.x; r < NBLK; r += BLOCK) {
    #pragma unroll
    for (int i = 0; i < 6; ++i) v[i] += (double)part[r * 6 + i];
  }
  #pragma unroll
  for (int off = 32; off > 0; off >>= 1) {
    #pragma unroll
    for (int i = 0; i < 6; ++i) v[i] += __shfl_down(v[i], off, 64);
  }
  __shared__ double red[4][6];
  const int w = threadIdx.x >> 6, lane = threadIdx.x & 63;
  if (lane == 0) {
    #pragma unroll
    for (int i = 0; i < 6; ++i) red[w][i] = v[i];
  }
  __syncthreads();
  if (threadIdx.x == 0) {
    double a[6];
    #pragma unroll
    for (int i = 0; i < 6; ++i) a[i] = red[0][i] + red[1][i] + red[2][i] + red[3][i];
    const double live_n = a[1] < 1.0 ? 1.0 : a[1];
    const double fire   = a[0] / live_n;                                   // LAM_FIRE   = 1.0
    const double cancel = (a[3] > 0.0) ? a[2] / (a[3] < 1.0 ? 1.0 : a[3])  // LAM_CANCEL = 1.0
                                       : 0.0;
    const double valid  = 0.5 * a[4] / live_n;                             // LAM_VALID  = 0.5
    const double wr     = 0.5 * a[5] / (double)ROWS;                       // LAM_WRITE  = 0.5
    out[0] = (float)fire;
    out[1] = (float)cancel;
    out[2] = (float)valid;
    out[3] = (float)wr;
    out[4] = (float)(fire + cancel + valid + wr);
  }
}

extern "C" void kernel_launch(void* const* d_in, const int* in_sizes, int n_in,
                              void* d_out, int out_size, void* d_ws, size_t ws_size,
                              hipStream_t stream) {
  const float* trig   = (const float*)d_in[0];
  const float* valp   = (const float*)d_in[1];
  const float* clog   = (const float*)d_in[2];
  const float* wscore = (const float*)d_in[3];
  const int*   live   = (const int*)  d_in[4];
  const int*   cid    = (const int*)  d_in[5];
  const float* ofire  = (const float*)d_in[6];
  const int*   ocan   = (const int*)  d_in[7];
  const float* ovalid = (const float*)d_in[8];
  const float* oshw   = (const float*)d_in[9];
  const int*   ocid   = (const int*)  d_in[10];
  float* out  = (float*)d_out;
  float* part = (float*)d_ws;   // NBLK*6 floats = 96 KB, fully overwritten

  loss_main<<<NBLK, BLOCK, 0, stream>>>(trig, valp, clog, wscore, live, cid,
                                        ofire, ocan, ovalid, oshw, ocid, part);
  loss_finalize<<<1, BLOCK, 0, stream>>>(part, out);
}